// Round 5
// baseline (460.010 us; speedup 1.0000x reference)
//
#include <hip/hip_runtime.h>
#include <math.h>

typedef unsigned short u16;
typedef __attribute__((ext_vector_type(8))) short bf16x8;     // 8 bf16 = 4 VGPRs (MFMA A/B frag)
typedef __attribute__((ext_vector_type(8))) unsigned short u16x8;
typedef __attribute__((ext_vector_type(4))) float f32x4;      // MFMA C/D frag

#define MFMA(a, b, c) __builtin_amdgcn_mfma_f32_16x16x32_bf16((a), (b), (c), 0, 0, 0)

// async global->LDS, 16B per lane; LDS dest = wave-uniform base + lane*16,
// global source = per-lane VGPR address (gather OK)
#define GLOAD_LDS16(g, l)                                                     \
  __builtin_amdgcn_global_load_lds(                                           \
      (const __attribute__((address_space(1))) void*)(g),                     \
      (__attribute__((address_space(3))) void*)(l), 16, 0, 0)

// DRAIN_VMEM: all in-flight global_load_lds landed in LDS (explicit, before barrier)
#define DRAIN_VMEM() asm volatile("s_waitcnt vmcnt(0)" ::: "memory")
// FENCE_LDS: order same-wave ds_write -> ds_read handoff (Pt) explicitly.
#define FENCE_LDS()                                                            \
  do {                                                                         \
    asm volatile("s_waitcnt lgkmcnt(0)" ::: "memory");                         \
    __builtin_amdgcn_sched_barrier(0);                                         \
  } while (0)

__device__ __forceinline__ float bf2f(u16 u) {
  union { unsigned int i; float f; } x; x.i = ((unsigned int)u) << 16; return x.f;
}
__device__ __forceinline__ u16 f2bf(float f) {
  union { float f; unsigned int i; } x; x.f = f;
  unsigned int r = x.i + 0x7FFFu + ((x.i >> 16) & 1u);   // round-to-nearest-even
  return (u16)(r >> 16);
}

// ---------------------------------------------------------------------------
// Dtype probes, one launch: flag[i]=1 bf16, 0 fp32.
// ---------------------------------------------------------------------------
__global__ __launch_bounds__(256) void probe_all(const u16* p0, const u16* p1,
                                                 const u16* p2, const u16* p3,
                                                 const u16* p4, const u16* p5,
                                                 int* __restrict__ flags) {
  const u16* ps[6] = {p0, p1, p2, p3, p4, p5};
  const u16* p = ps[blockIdx.x];
  __shared__ int cnt;
  if (threadIdx.x == 0) cnt = 0;
  __syncthreads();
  const u16 u = p[threadIdx.x * 2];
  const int e = (u >> 7) & 0xFF;
  atomicAdd(&cnt, (e >= 110 && e <= 135) ? 1 : 0);
  __syncthreads();
  if (threadIdx.x == 0) flags[blockIdx.x] = (cnt > 128) ? 1 : 0;
}

// ---------------------------------------------------------------------------
// prep_all: merged bf16 canonicalization of x + 4 weights, plus mexp build.
// ---------------------------------------------------------------------------
__global__ __launch_bounds__(256) void prep_all(const void* __restrict__ x_in,
                                                const void* __restrict__ wq_in,
                                                const void* __restrict__ wk_in,
                                                const void* __restrict__ wv_in,
                                                const void* __restrict__ wo_in,
                                                const void* __restrict__ mask_in,
                                                u16* __restrict__ xc,
                                                float* __restrict__ mexp,
                                                const int* __restrict__ flags) {
  const int blk = blockIdx.x;
  if (blk < 12288) {
    const int i = blk * 256 + threadIdx.x;
    const void* in; u16* out; int fi, off;
    if (i < (1 << 20)) {                 // x: NX/8 = 2^20 vec8 elems
      in = x_in; out = xc; fi = 0; off = i;
    } else {
      const int k = i - (1 << 20);
      const int seg = k >> 19;           // each W: NW/8 = 2^19 vec8 elems
      off = k & ((1 << 19) - 1);
      in = (seg == 0) ? wq_in : (seg == 1) ? wk_in : (seg == 2) ? wv_in : wo_in;
      out = xc + ((size_t)1 << 23) + ((size_t)seg << 22);  // Wqc..Woc contiguous
      fi = 2 + seg;
    }
    if (flags[fi]) {
      ((u16x8*)out)[off] = ((const u16x8*)in)[off];
    } else {
      const float* f = (const float*)in + (size_t)off * 8;
      u16x8 r;
#pragma unroll
      for (int j = 0; j < 8; ++j) r[j] = f2bf(f[j]);
      ((u16x8*)out)[off] = r;
    }
  } else {
    const int i = (blk - 12288) * 256 + threadIdx.x;   // 0..4095
    const float m = flags[1] ? bf2f(((const u16*)mask_in)[i]) : ((const float*)mask_in)[i];
    mexp[i] = (1.0f - m) * -1e9f;
  }
}

// ---------------------------------------------------------------------------
// gemm256: 256x256 tile, BK=64, 8 waves (2M x 4N), 8-phase schedule with
// counted vmcnt (T3+T4) + setprio (T5). C[M,N] = A[M,K] @ B[N,K]^T, bf16.
//
// Wave wr in {0,1} owns rows {wr*64..+63} U {128+wr*64..+63}; wc in {0..3}
// owns cols {wc*32..+31} U {128+wc*32..+31}. Thus quadrant (qm,qn) phase
// collectively consumes exactly staging-half A[qm] (rows qm*128..+127) and
// B[qn] -- each phase frees one 16KB half for overwrite.
//
// Per 8-phase iteration (tiles a=2i in buf0 @P1-4, b=2i+1 in buf1 @P5-8;
// quadrant order Q00,Q10,Q01,Q11):
//   P1 stage A1(b)->buf1  P2 B1(b)->buf1  P3 B0(a+2)->buf0  P4 A0(a+2)->buf0
//   P5 A1(a+2)->buf0      P6 B1(a+2)->buf0 P7 B0(b+2)->buf1 P8 A0(b+2)->buf1
// Write-after-read safety (region last read -> staged): buf1.A1 read P6,P8
// prev iter -> P1; buf0.B0 read P1,P2 -> P3; buf0.A0 read P1,P3 -> P4;
// buf0.A1 read P2,P4 -> P5; buf0.B1 read P3,P4 -> P6; buf1.B0 read P5,P6
// -> P7; buf1.A0 read P5,P7 -> P8; buf1.B1 read P7,P8 -> P2 next. All
// separated by >=1 end-of-phase barrier.
// vmcnt(4) @P4 retires everything except P3,P4 stages -> covers P5-P8 reads
// (b's A0@P8prev,B0@P7prev,A1@P1,B1@P2). vmcnt(4) @P8 covers next P1-P4.
// Last iteration (no P3-P8 stages) uses vmcnt(0) instead.
// LDS 128 KB (2buf x 2half x 128x64 x {A,B}) -> 1 block/CU, 2 waves/SIMD.
// XOR chunk swizzle c^(r&7) on 16B chunks (measured 0 bank conflicts).
// mode 2: fp32 out [M,2048]. mode 3: QKV fused N=6144 band decode.
// ---------------------------------------------------------------------------
#define G_STGA(SB, H, T)                                                          \
  do {                                                                            \
    GLOAD_LDS16(Ag + (bi + (H) * 128 + rr[0]) * (size_t)K + (T) * 64 + cc[0] * 8, \
                &As[SB][H][lofs[0]]);                                             \
    GLOAD_LDS16(Ag + (bi + (H) * 128 + rr[1]) * (size_t)K + (T) * 64 + cc[1] * 8, \
                &As[SB][H][lofs[1]]);                                             \
  } while (0)

#define G_STGB(SB, H, T)                                                          \
  do {                                                                            \
    GLOAD_LDS16(Bg + (bj + (H) * 128 + rr[0]) * (size_t)K + (T) * 64 + cc[0] * 8, \
                &Bs[SB][H][lofs[0]]);                                             \
    GLOAD_LDS16(Bg + (bj + (H) * 128 + rr[1]) * (size_t)K + (T) * 64 + cc[1] * 8, \
                &Bs[SB][H][lofs[1]]);                                             \
  } while (0)

#define G_LDA(CB, QM)                                                          \
  do {                                                                         \
    _Pragma("unroll") for (int mf = 0; mf < 4; ++mf)                           \
    _Pragma("unroll") for (int kk = 0; kk < 2; ++kk) {                         \
      const int lr = wr64 + mf * 16 + m16;                                     \
      af[mf][kk] = *(const bf16x8*)&As[CB][QM]                                 \
          [lr * 64 + (((kk * 4 + quad) ^ (lr & 7)) * 8)];                      \
    }                                                                          \
  } while (0)

#define G_LDB(CB, QN)                                                          \
  do {                                                                         \
    _Pragma("unroll") for (int nf = 0; nf < 2; ++nf)                           \
    _Pragma("unroll") for (int kk = 0; kk < 2; ++kk) {                         \
      const int lr = wc32 + nf * 16 + m16;                                     \
      bfr[nf][kk] = *(const bf16x8*)&Bs[CB][QN]                                \
          [lr * 64 + (((kk * 4 + quad) ^ (lr & 7)) * 8)];                      \
    }                                                                          \
  } while (0)

// barrier -> lgkmcnt(0)+sched_barrier (rule #18) -> setprio-wrapped 16 MFMA
// -> barrier. End barrier is the write-after-read separator.
#define G_SYNC_MM(QM, QN)                                                      \
  do {                                                                         \
    __builtin_amdgcn_s_barrier();                                              \
    asm volatile("s_waitcnt lgkmcnt(0)" ::: "memory");                         \
    __builtin_amdgcn_sched_barrier(0);                                         \
    __builtin_amdgcn_s_setprio(1);                                             \
    _Pragma("unroll") for (int mf = 0; mf < 4; ++mf)                           \
    _Pragma("unroll") for (int nf = 0; nf < 2; ++nf)                           \
    _Pragma("unroll") for (int kk = 0; kk < 2; ++kk)                           \
      acc[(QM) * 4 + mf][(QN) * 2 + nf] =                                      \
          MFMA(af[mf][kk], bfr[nf][kk], acc[(QM) * 4 + mf][(QN) * 2 + nf]);    \
    __builtin_amdgcn_s_setprio(0);                                             \
    __builtin_amdgcn_s_barrier();                                              \
  } while (0)

__global__ __launch_bounds__(512, 2) void gemm256(const u16* __restrict__ Ag,
                                                  const u16* __restrict__ Bg,
                                                  void* __restrict__ dst,
                                                  int K, int mode) {
  __shared__ __align__(16) u16 As[2][2][128 * 64];   // [buf][half][r*64+c] 64 KB
  __shared__ __align__(16) u16 Bs[2][2][128 * 64];   // 64 KB
  const int tid  = threadIdx.x;
  const int wid  = tid >> 6, lane = tid & 63;
  const int quad = lane >> 4, m16 = lane & 15;
  const int wr64 = (wid >> 2) * 64;    // M-side wave offset within a half
  const int wc32 = (wid & 3) * 32;     // N-side wave offset within a half
  const size_t bi = (size_t)blockIdx.y * 256;
  const size_t bj = (size_t)blockIdx.x * 256;

  // staging descriptors: 2 x 16B chunks per wave per half-tile
  int rr[2], cc[2], lofs[2];
#pragma unroll
  for (int j = 0; j < 2; ++j) {
    const int t = (wid * 2 + j) * 64 + lane;   // 0..1023 chunk id in half-tile
    rr[j]   = t >> 3;                          // local row 0..127
    cc[j]   = (t & 7) ^ (rr[j] & 7);           // global chunk (pre-swizzled src)
    lofs[j] = t * 8;                           // linear LDS dest (u16 elems)
  }

  f32x4 acc[8][4];
  const f32x4 fz = {0.f, 0.f, 0.f, 0.f};
#pragma unroll
  for (int i = 0; i < 8; ++i)
#pragma unroll
    for (int j = 0; j < 4; ++j) acc[i][j] = fz;

  bf16x8 af[4][2], bfr[2][2];

  // prologue == steady-state history of iter -1: tile0 {B0,A0,A1,B1}, tile1 {B0,A0}
  G_STGB(0, 0, 0); G_STGA(0, 0, 0); G_STGA(0, 1, 0); G_STGB(0, 1, 0);
  G_STGB(1, 0, 1); G_STGA(1, 0, 1);
  asm volatile("s_waitcnt vmcnt(4)" ::: "memory");   // tile0 landed; tile1 flying
  __builtin_amdgcn_s_barrier();

  const int nIter = K >> 7;               // 2 K-tiles (128 K) per iteration
  for (int i = 0; i < nIter; ++i) {
    const int tb = 2 * i + 1, ta2 = 2 * i + 2, tb2 = 2 * i + 3;
    const bool more = (i + 1 < nIter);
    // P1: Q00 of buf0
    G_LDA(0, 0); G_LDB(0, 0);
    G_STGA(1, 1, tb);
    G_SYNC_MM(0, 0);
    // P2: Q10 of buf0 (reuse B0 frags)
    G_LDA(0, 1);
    G_STGB(1, 1, tb);
    G_SYNC_MM(1, 0);
    // P3: Q01 of buf0
    G_LDA(0, 0); G_LDB(0, 1);
    if (more) G_STGB(0, 0, ta2);
    G_SYNC_MM(0, 1);
    // P4: Q11 of buf0 (reuse B1); counted vmcnt covers P5-P8 reads
    G_LDA(0, 1);
    if (more) { G_STGA(0, 0, ta2);
                asm volatile("s_waitcnt vmcnt(4)" ::: "memory"); }
    else      { asm volatile("s_waitcnt vmcnt(0)" ::: "memory"); }
    G_SYNC_MM(1, 1);
    // P5: Q00 of buf1
    G_LDA(1, 0); G_LDB(1, 0);
    if (more) G_STGA(0, 1, ta2);
    G_SYNC_MM(0, 0);
    // P6: Q10 of buf1
    G_LDA(1, 1);
    if (more) G_STGB(0, 1, ta2);
    G_SYNC_MM(1, 0);
    // P7: Q01 of buf1
    G_LDA(1, 0); G_LDB(1, 1);
    if (more) G_STGB(1, 0, tb2);
    G_SYNC_MM(0, 1);
    // P8: Q11 of buf1; counted vmcnt covers next iter's P1-P4 reads
    G_LDA(1, 1);
    if (more) { G_STGA(1, 0, tb2);
                asm volatile("s_waitcnt vmcnt(4)" ::: "memory"); }
    else      { asm volatile("s_waitcnt vmcnt(0)" ::: "memory"); }
    G_SYNC_MM(1, 1);
  }

  // epilogue: C/D layout col=lane&15, row=quad*4+reg (m89/m91-verified)
#pragma unroll
  for (int ai = 0; ai < 8; ++ai) {
#pragma unroll
    for (int bq = 0; bq < 4; ++bq) {
#pragma unroll
      for (int rg = 0; rg < 4; ++rg) {
        const int row = (int)bi + (ai >> 2) * 128 + wr64 + (ai & 3) * 16 + quad * 4 + rg;
        const int col = (int)bj + (bq >> 1) * 128 + wc32 + (bq & 1) * 16 + m16;
        const float v = acc[ai][bq][rg];
        if (mode == 2) {
          ((float*)dst)[(size_t)row * 2048 + col] = v;           // FP32 out
        } else {
          // QKV fused: band 0=Q, 1=K (both [B,H,S,D]); 2=V ([B,H,D,S])
          const int band = col >> 11, lc = col & 2047;
          const int bb = row >> 11, s = row & 2047, hh = lc >> 7, dd = lc & 127;
          const size_t bandbase = (size_t)band * 8388608u;       // NX elems
          const size_t idx = (band == 2)
              ? bandbase + ((((size_t)bb * 16 + hh) * 128 + dd) * 2048 + s)
              : bandbase + ((((size_t)bb * 16 + hh) * 2048 + s) * 128 + dd);
          ((u16*)dst)[idx] = f2bf(v);
        }
      }
    }
  }
}

// ---------------------------------------------------------------------------
// RoPE in-place on Q,K [B,H,S,D=128] (bf16); folds 1/sqrt(128) into Q.
// ---------------------------------------------------------------------------
__global__ __launch_bounds__(256) void rope_kernel(u16* __restrict__ Qr,
                                                   u16* __restrict__ Kr) {
  const int tid = blockIdx.x * 256 + threadIdx.x;   // B*H*S*64 total
  const int j  = tid & 63;
  const int s  = (tid >> 6) & 2047;
  const int bh = tid >> 17;
  const size_t base = ((size_t)bh * 2048 + s) * 128;
  const float freq = __expf(-(float)j * (9.2103403719761836f / 64.0f));
  float sn, cs;
  sincosf((float)s * freq, &sn, &cs);
  const float qs = 0.08838834764831845f;  // 1/sqrt(128)
  const float q1 = bf2f(Qr[base + j]), q2 = bf2f(Qr[base + j + 64]);
  Qr[base + j]      = f2bf((q1 * cs - q2 * sn) * qs);
  Qr[base + j + 64] = f2bf((q2 * cs + q1 * sn) * qs);
  const float k1 = bf2f(Kr[base + j]), k2 = bf2f(Kr[base + j + 64]);
  Kr[base + j]      = f2bf(k1 * cs - k2 * sn);
  Kr[base + j + 64] = f2bf(k2 * cs + k1 * sn);
}

// ---------------------------------------------------------------------------
// Flash v5 (unchanged from passing round-4 run): balanced qtile-pairs,
// 64 Q-rows/block, LDS 56 KB -> 2 blocks/CU, K dbuf + single-buffered V with
// counted mid-iter vmcnt(4).
// ---------------------------------------------------------------------------
__global__ __launch_bounds__(256, 2) void flash_attn(const u16* __restrict__ Q,
                                                     const u16* __restrict__ Kg,
                                                     const u16* __restrict__ Vg,
                                                     const float* __restrict__ mexp_g,
                                                     u16* __restrict__ ctx) {
  const int S = 2048, D = 128;
  __shared__ __align__(16) u16 Kt[2][64 * 128];   // [buf][key r][d], chunk swz
  __shared__ __align__(16) u16 Vt[128 * 64];      // [d][key], chunk swz, single buf
  __shared__ __align__(16) u16 Pt[64 * 64];       // [row][key], chunk swz
  const int tid  = threadIdx.x;
  const int wave = tid >> 6, lane = tid & 63;
  const int quad = lane >> 4, m16 = lane & 15;
  const int px = blockIdx.x >> 1;        // qtile pair index 0..7
  const int hl = blockIdx.x & 1;         // 64-row half within the qtile
  const int bh = blockIdx.y;
  const int b = bh >> 4, h = bh & 15;
  const size_t baseQK = (size_t)bh * S * D;
  const size_t baseV  = (size_t)bh * D * S;

  const u16* gK[4]; const u16* gV[4]; int lK[4], lV[4];
#pragma unroll
  for (int j = 0; j < 4; ++j) {
    const int t = (wave * 4 + j) * 64 + lane;    // linear 16B-chunk id
    {
      const int r = t >> 4, cs = t & 15;
      const int c = (cs & 8) | ((cs ^ r) & 7);   // global chunk (0..15)
      gK[j] = Kg + baseQK + (size_t)r * D + c * 8;   // + k0*D per tile
      lK[j] = t * 8;
    }
    {
      const int d = t >> 3, cs = t & 7;
      const int c = cs ^ (d & 7);                // global chunk (0..7)
      gV[j] = Vg + baseV + (size_t)d * S + c * 8;    // + k0 per tile
      lV[j] = t * 8;
    }
  }

  const f32x4 fz = {0.f, 0.f, 0.f, 0.f};

  for (int pass = 0; pass < 2; ++pass) {
    const int qtile = pass ? px : 15 - px;     // heavy first
    const int q0 = qtile * 128 + hl * 64;
    const int ktmax = 2 * qtile + hl;

    __syncthreads();

    bf16x8 qf[4];
#pragma unroll
    for (int kb = 0; kb < 4; ++kb)
      qf[kb] = *(const bf16x8*)&Q[baseQK +
          (size_t)(q0 + wave * 16 + m16) * D + kb * 32 + quad * 8];

    float li[4] = {0.f, 0.f, 0.f, 0.f};
    f32x4 oacc[8];
#pragma unroll
    for (int dt = 0; dt < 8; ++dt) oacc[dt] = fz;

#pragma unroll
    for (int j = 0; j < 4; ++j) GLOAD_LDS16(gK[j], &Kt[0][lK[j]]);

    for (int kt = 0; kt <= ktmax; ++kt) {
      const int k0 = kt * 64;
      const int cb = kt & 1;
      DRAIN_VMEM();
      __syncthreads();   // K(kt) resident; all waves done with Vt(kt-1), Kt[cb^1]

#pragma unroll
      for (int j = 0; j < 4; ++j) GLOAD_LDS16(gV[j] + k0, &Vt[lV[j]]);
      float madd[4];
#pragma unroll
      for (int nt = 0; nt < 4; ++nt)
        madd[nt] = mexp_g[b * S + k0 + nt * 16 + m16];
      if (kt < ktmax) {
#pragma unroll
        for (int j = 0; j < 4; ++j)
          GLOAD_LDS16(gK[j] + (size_t)(k0 + 64) * D, &Kt[cb ^ 1][lK[j]]);
      }

      f32x4 sacc[4];
#pragma unroll
      for (int nt = 0; nt < 4; ++nt) sacc[nt] = fz;
#pragma unroll
      for (int nt = 0; nt < 4; ++nt)
#pragma unroll
        for (int kb = 0; kb < 4; ++kb) {
          const int c = kb * 4 + quad;
          const int cs = (c & 8) | ((c ^ m16) & 7);
          bf16x8 kf = *(const bf16x8*)&Kt[cb][(nt * 16 + m16) * 128 + cs * 8];
          sacc[nt] = MFMA(qf[kb], kf, sacc[nt]);
        }

      if (kt < ktmax) { asm volatile("s_waitcnt vmcnt(4)" ::: "memory"); }
      else           { asm volatile("s_waitcnt vmcnt(0)" ::: "memory"); }
      __builtin_amdgcn_sched_barrier(0);

      const int R0   = q0 + wave * 16;
      const int prow = wave * 16 + quad * 4;
      if (k0 + 63 > R0) {
#pragma unroll
        for (int rg = 0; rg < 4; ++rg) {
          const int row = R0 + quad * 4 + rg;
          const int pr  = prow + rg;
          float ps = 0.f;
#pragma unroll
          for (int nt = 0; nt < 4; ++nt) {
            const int col = k0 + nt * 16 + m16;
            const float p = (col > row) ? 0.f : __expf(sacc[nt][rg] + madd[nt]);
            ps += p;
            const int c = nt * 2 + (m16 >> 3);
            Pt[pr * 64 + ((c ^ pr) & 7) * 8 + (m16 & 7)] = f2bf(p);
          }
          li[rg] += ps;
        }
      } else {
#pragma unroll
        for (int rg = 0; rg < 4; ++rg) {
          const int pr = prow + rg;
          float ps = 0.f;
#pragma unroll
          for (int nt = 0; nt < 4; ++nt) {
            const float p = __expf(sacc[nt][rg] + madd[nt]);
            ps += p;
            const int c = nt * 2 + (m16 >> 3);
            Pt[pr * 64 + ((c ^ pr) & 7) * 8 + (m16 & 7)] = f2bf(p);
          }
          li[rg] += ps;
        }
      }
      FENCE_LDS();

#pragma unroll
      for (int kb = 0; kb < 2; ++kb) {
        const int c = kb * 4 + quad;
        const int cs = (c ^ m16) & 7;
        bf16x8 pf = *(const bf16x8*)&Pt[(wave * 16 + m16) * 64 + cs * 8];
#pragma unroll
        for (int dt = 0; dt < 8; ++dt) {
          bf16x8 vf = *(const bf16x8*)&Vt[(dt * 16 + m16) * 64 + cs * 8];
          oacc[dt] = MFMA(pf, vf, oacc[dt]);
        }
      }
    }

#pragma unroll
    for (int rg = 0; rg < 4; ++rg) {
      float ls = li[rg];
#pragma unroll
      for (int mk = 1; mk < 16; mk <<= 1) ls += __shfl_xor(ls, mk, 64);
      const float inv = 1.0f / ls;
      const int srow = q0 + wave * 16 + quad * 4 + rg;
#pragma unroll
      for (int dt = 0; dt < 8; ++dt) {
        const int e = h * 128 + dt * 16 + m16;
        ctx[((size_t)b * S + srow) * 2048 + e] = f2bf(oacc[dt][rg] * inv);
      }
    }
  }
}

// ---------------------------------------------------------------------------
extern "C" void kernel_launch(void* const* d_in, const int* in_sizes, int n_in,
                              void* d_out, int out_size, void* d_ws, size_t ws_size,
                              hipStream_t stream) {
  (void)in_sizes; (void)n_in; (void)out_size; (void)ws_size;
  const int Bz = 2, S = 2048, E = 2048, H = 16;
  const size_t NX = (size_t)Bz * S * E;   // 8388608
  const size_t NW = (size_t)E * E;        // 4194304

  // ws layout (~117.5 MB)
  char* ws = (char*)d_ws;
  int*   flags = (int*)ws;                 // 6 ints
  float* mexp  = (float*)(ws + 256);       // 16 KB
  u16* xc  = (u16*)(ws + 256 + 16384);
  u16* Wqc = xc + NX;                      // Wq,Wk,Wv contiguous = fused B
  u16* Qr  = Wqc + 4 * NW;                 // [B,H,S,D]; Qr,Kr,Vt contiguous
  u16* Kr  = Qr + NX;                      // [B,H,S,D]
  u16* Vt  = Kr + NX;                      // [B,H,D,S]
  u16* ctx = Vt + NX;                      // [B,S,E]
  u16* Woc = Wqc + 3 * NW;

  probe_all<<<6, 256, 0, stream>>>((const u16*)d_in[0], (const u16*)d_in[1],
                                   (const u16*)d_in[2], (const u16*)d_in[3],
                                   (const u16*)d_in[4], (const u16*)d_in[5], flags);

  prep_all<<<12304, 256, 0, stream>>>(d_in[0], d_in[2], d_in[3], d_in[4],
                                      d_in[5], d_in[1], xc, mexp, flags);

  // fused QKV projection: C[4096, 6144] = xc @ [Wq;Wk;Wv]^T  (256^2 8-phase)
  gemm256<<<dim3(24, 16), 512, 0, stream>>>(xc, Wqc, Qr, E, 3);
  rope_kernel<<<(Bz * H * S * 64) / 256, 256, 0, stream>>>(Qr, Kr);
  flash_attn<<<dim3(16, Bz * H), 256, 0, stream>>>(Qr, Kr, Vt, mexp, ctx);
  gemm256<<<dim3(8, 16), 512, 0, stream>>>(ctx, Woc, d_out, E, 2);
}

// Round 12
// 413.180 us; speedup vs baseline: 1.1133x; 1.1133x over previous
//
#include <hip/hip_runtime.h>
#include <math.h>

typedef unsigned short u16;
typedef __attribute__((ext_vector_type(8))) short bf16x8;     // 8 bf16 = 4 VGPRs (MFMA A/B frag)
typedef __attribute__((ext_vector_type(8))) unsigned short u16x8;
typedef __attribute__((ext_vector_type(4))) float f32x4;      // MFMA C/D frag

#define MFMA(a, b, c) __builtin_amdgcn_mfma_f32_16x16x32_bf16((a), (b), (c), 0, 0, 0)

// async global->LDS, 16B per lane; LDS dest = wave-uniform base + lane*16,
// global source = per-lane VGPR address (gather OK)
#define GLOAD_LDS16(g, l)                                                     \
  __builtin_amdgcn_global_load_lds(                                           \
      (const __attribute__((address_space(1))) void*)(g),                     \
      (__attribute__((address_space(3))) void*)(l), 16, 0, 0)

// DRAIN_VMEM: all in-flight global_load_lds landed in LDS (explicit, before barrier)
#define DRAIN_VMEM() asm volatile("s_waitcnt vmcnt(0)" ::: "memory")
// FENCE_LDS: order same-wave ds_write -> ds_read handoff (Pt) explicitly.
#define FENCE_LDS()                                                            \
  do {                                                                         \
    asm volatile("s_waitcnt lgkmcnt(0)" ::: "memory");                         \
    __builtin_amdgcn_sched_barrier(0);                                         \
  } while (0)

__device__ __forceinline__ float bf2f(u16 u) {
  union { unsigned int i; float f; } x; x.i = ((unsigned int)u) << 16; return x.f;
}
__device__ __forceinline__ u16 f2bf(float f) {
  union { float f; unsigned int i; } x; x.f = f;
  unsigned int r = x.i + 0x7FFFu + ((x.i >> 16) & 1u);   // round-to-nearest-even
  return (u16)(r >> 16);
}

// ---------------------------------------------------------------------------
// Dtype probes, one launch: flag[i]=1 bf16, 0 fp32.
// ---------------------------------------------------------------------------
__global__ __launch_bounds__(256) void probe_all(const u16* p0, const u16* p1,
                                                 const u16* p2, const u16* p3,
                                                 const u16* p4, const u16* p5,
                                                 int* __restrict__ flags) {
  const u16* ps[6] = {p0, p1, p2, p3, p4, p5};
  const u16* p = ps[blockIdx.x];
  __shared__ int cnt;
  if (threadIdx.x == 0) cnt = 0;
  __syncthreads();
  const u16 u = p[threadIdx.x * 2];
  const int e = (u >> 7) & 0xFF;
  atomicAdd(&cnt, (e >= 110 && e <= 135) ? 1 : 0);
  __syncthreads();
  if (threadIdx.x == 0) flags[blockIdx.x] = (cnt > 128) ? 1 : 0;
}

// ---------------------------------------------------------------------------
// prep_all: merged bf16 canonicalization of x + 4 weights, plus mexp build.
// blocks [0, 12288): converts (x: 4096 blocks, then Wq/Wk/Wv/Wo: 2048 each,
// outputs contiguous from xc). blocks [12288, 12304): mexp.
// ---------------------------------------------------------------------------
__global__ __launch_bounds__(256) void prep_all(const void* __restrict__ x_in,
                                                const void* __restrict__ wq_in,
                                                const void* __restrict__ wk_in,
                                                const void* __restrict__ wv_in,
                                                const void* __restrict__ wo_in,
                                                const void* __restrict__ mask_in,
                                                u16* __restrict__ xc,
                                                float* __restrict__ mexp,
                                                const int* __restrict__ flags) {
  const int blk = blockIdx.x;
  if (blk < 12288) {
    const int i = blk * 256 + threadIdx.x;
    const void* in; u16* out; int fi, off;
    if (i < (1 << 20)) {                 // x: NX/8 = 2^20 vec8 elems
      in = x_in; out = xc; fi = 0; off = i;
    } else {
      const int k = i - (1 << 20);
      const int seg = k >> 19;           // each W: NW/8 = 2^19 vec8 elems
      off = k & ((1 << 19) - 1);
      in = (seg == 0) ? wq_in : (seg == 1) ? wk_in : (seg == 2) ? wv_in : wo_in;
      out = xc + ((size_t)1 << 23) + ((size_t)seg << 22);  // Wqc..Woc contiguous
      fi = 2 + seg;
    }
    if (flags[fi]) {
      ((u16x8*)out)[off] = ((const u16x8*)in)[off];
    } else {
      const float* f = (const float*)in + (size_t)off * 8;
      u16x8 r;
#pragma unroll
      for (int j = 0; j < 8; ++j) r[j] = f2bf(f[j]);
      ((u16x8*)out)[off] = r;
    }
  } else {
    const int i = (blk - 12288) * 256 + threadIdx.x;   // 0..4095
    const float m = flags[1] ? bf2f(((const u16*)mask_in)[i]) : ((const float*)mask_in)[i];
    mexp[i] = (1.0f - m) * -1e9f;
  }
}

// ---------------------------------------------------------------------------
// GEMM: C[M,N] = A[M,K] @ B[N,K]^T, bf16 in. 128x128 tile, BK=64,
// double-buffered global_load_lds staging, single barrier per K-iter.
// XOR-swizzled unpadded LDS: chunk c of row r stored at c^(r&7).
// mode 2: fp32 out [M,2048]
// mode 3: QKV fused, N=6144; col band 0/1 -> bf16 [B,H,S,D] (Q/K),
//         band 2 -> bf16 [B,H,D,S] (V^T). dst = Qr (Qr,Kr,Vt contiguous).
// ---------------------------------------------------------------------------
__global__ __launch_bounds__(256) void gemm_bt(const u16* __restrict__ A,
                                               const u16* __restrict__ B,
                                               void* __restrict__ dst,
                                               int K, int mode) {
  __shared__ __align__(16) u16 As[2][128 * 64];   // 32 KB
  __shared__ __align__(16) u16 Bs[2][128 * 64];   // 32 KB
  const int tid  = threadIdx.x;
  const int wave = tid >> 6, lane = tid & 63;
  const int quad = lane >> 4, m16 = lane & 15;
  const int wm = (wave >> 1) * 64, wn = (wave & 1) * 64;
  const size_t bi = (size_t)blockIdx.y * 128;
  const size_t bj = (size_t)blockIdx.x * 128;

  f32x4 acc[4][4];
  const f32x4 fz = {0.f, 0.f, 0.f, 0.f};
#pragma unroll
  for (int i = 0; i < 4; ++i)
#pragma unroll
    for (int j = 0; j < 4; ++j) acc[i][j] = fz;

  // staging descriptors: 4 chunks A + 4 chunks B per wave, fixed across K
  const u16* gA[4]; const u16* gB[4]; int lofs[4];
#pragma unroll
  for (int j = 0; j < 4; ++j) {
    const int t  = (wave * 4 + j) * 64 + lane;   // linear chunk id in tile
    const int r  = t >> 3;                       // tile row
    const int cs = t & 7;                        // stored (swizzled) chunk
    const int c  = cs ^ (r & 7);                 // global chunk
    gA[j] = A + (bi + r) * (size_t)K + c * 8;
    gB[j] = B + (bj + r) * (size_t)K + c * 8;
    lofs[j] = t * 8;
  }

  // prologue: stage K-tile 0 into buffer 0
#pragma unroll
  for (int j = 0; j < 4; ++j) GLOAD_LDS16(gA[j], &As[0][lofs[j]]);
#pragma unroll
  for (int j = 0; j < 4; ++j) GLOAD_LDS16(gB[j], &Bs[0][lofs[j]]);

  const int nIter = K >> 6;
  for (int it = 0; it < nIter; ++it) {
    DRAIN_VMEM();                         // cur-buf loads landed in LDS
    __syncthreads();                      // all waves done with other buf
    if (it + 1 < nIter) {
      const int ko = (it + 1) << 6;
      const int nb = (it + 1) & 1;
#pragma unroll
      for (int j = 0; j < 4; ++j) GLOAD_LDS16(gA[j] + ko, &As[nb][lofs[j]]);
#pragma unroll
      for (int j = 0; j < 4; ++j) GLOAD_LDS16(gB[j] + ko, &Bs[nb][lofs[j]]);
    }
    const int cb = it & 1;

    bf16x8 af[2][4], bfv[2][4];
#pragma unroll
    for (int kk = 0; kk < 2; ++kk) {
#pragma unroll
      for (int mt = 0; mt < 4; ++mt) {
        const int m = wm + mt * 16 + m16;
        af[kk][mt] = *(const bf16x8*)&As[cb][m * 64 + ((kk * 4 + quad) ^ (m & 7)) * 8];
      }
#pragma unroll
      for (int nt = 0; nt < 4; ++nt) {
        const int n = wn + nt * 16 + m16;
        bfv[kk][nt] = *(const bf16x8*)&Bs[cb][n * 64 + ((kk * 4 + quad) ^ (n & 7)) * 8];
      }
    }
#pragma unroll
    for (int kk = 0; kk < 2; ++kk)
#pragma unroll
      for (int mt = 0; mt < 4; ++mt)
#pragma unroll
        for (int nt = 0; nt < 4; ++nt)
          acc[mt][nt] = MFMA(af[kk][mt], bfv[kk][nt], acc[mt][nt]);
  }

  // epilogue: C/D layout col=lane&15, row=quad*4+reg (m89/m91-verified)
#pragma unroll
  for (int mt = 0; mt < 4; ++mt) {
#pragma unroll
    for (int nt = 0; nt < 4; ++nt) {
#pragma unroll
      for (int rg = 0; rg < 4; ++rg) {
        const int row = (int)bi + wm + mt * 16 + quad * 4 + rg;  // b*2048+s
        const int col = (int)bj + wn + nt * 16 + m16;
        const float v = acc[mt][nt][rg];
        if (mode == 2) {
          ((float*)dst)[(size_t)row * 2048 + col] = v;           // FP32 out
        } else {
          // QKV fused: band 0=Q, 1=K (both [B,H,S,D]); 2=V ([B,H,D,S])
          const int band = col >> 11, lc = col & 2047;
          const int bb = row >> 11, s = row & 2047, hh = lc >> 7, dd = lc & 127;
          const size_t bandbase = (size_t)band * 8388608u;       // NX elems
          const size_t idx = (band == 2)
              ? bandbase + ((((size_t)bb * 16 + hh) * 128 + dd) * 2048 + s)
              : bandbase + ((((size_t)bb * 16 + hh) * 2048 + s) * 128 + dd);
          ((u16*)dst)[idx] = f2bf(v);
        }
      }
    }
  }
}

// ---------------------------------------------------------------------------
// RoPE in-place on Q,K [B,H,S,D=128] (bf16); folds 1/sqrt(128) into Q.
// (scalar round-4 verified version)
// ---------------------------------------------------------------------------
__global__ __launch_bounds__(256) void rope_kernel(u16* __restrict__ Qr,
                                                   u16* __restrict__ Kr) {
  const int tid = blockIdx.x * 256 + threadIdx.x;   // B*H*S*64 total
  const int j  = tid & 63;
  const int s  = (tid >> 6) & 2047;
  const int bh = tid >> 17;
  const size_t base = ((size_t)bh * 2048 + s) * 128;
  const float freq = __expf(-(float)j * (9.2103403719761836f / 64.0f));
  float sn, cs;
  sincosf((float)s * freq, &sn, &cs);
  const float qs = 0.08838834764831845f;  // 1/sqrt(128)
  const float q1 = bf2f(Qr[base + j]), q2 = bf2f(Qr[base + j + 64]);
  Qr[base + j]      = f2bf((q1 * cs - q2 * sn) * qs);
  Qr[base + j + 64] = f2bf((q2 * cs + q1 * sn) * qs);
  const float k1 = bf2f(Kr[base + j]), k2 = bf2f(Kr[base + j + 64]);
  Kr[base + j]      = f2bf(k1 * cs - k2 * sn);
  Kr[base + j + 64] = f2bf(k2 * cs + k1 * sn);
}

// ---------------------------------------------------------------------------
// Flash v5: balanced qtile-pairs, 64 Q-rows/block, LDS 56 KB -> 2 blocks/CU,
// K dbuf + single-buffered V with counted mid-iter vmcnt(4).
// ---------------------------------------------------------------------------
__global__ __launch_bounds__(256, 2) void flash_attn(const u16* __restrict__ Q,
                                                     const u16* __restrict__ Kg,
                                                     const u16* __restrict__ Vg,
                                                     const float* __restrict__ mexp_g,
                                                     u16* __restrict__ ctx) {
  const int S = 2048, D = 128;
  __shared__ __align__(16) u16 Kt[2][64 * 128];   // [buf][key r][d], chunk swz
  __shared__ __align__(16) u16 Vt[128 * 64];      // [d][key], chunk swz, single buf
  __shared__ __align__(16) u16 Pt[64 * 64];       // [row][key], chunk swz
  const int tid  = threadIdx.x;
  const int wave = tid >> 6, lane = tid & 63;
  const int quad = lane >> 4, m16 = lane & 15;
  const int px = blockIdx.x >> 1;        // qtile pair index 0..7
  const int hl = blockIdx.x & 1;         // 64-row half within the qtile
  const int bh = blockIdx.y;
  const int b = bh >> 4, h = bh & 15;
  const size_t baseQK = (size_t)bh * S * D;
  const size_t baseV  = (size_t)bh * D * S;

  const u16* gK[4]; const u16* gV[4]; int lK[4], lV[4];
#pragma unroll
  for (int j = 0; j < 4; ++j) {
    const int t = (wave * 4 + j) * 64 + lane;    // linear 16B-chunk id
    {
      const int r = t >> 4, cs = t & 15;
      const int c = (cs & 8) | ((cs ^ r) & 7);   // global chunk (0..15)
      gK[j] = Kg + baseQK + (size_t)r * D + c * 8;   // + k0*D per tile
      lK[j] = t * 8;
    }
    {
      const int d = t >> 3, cs = t & 7;
      const int c = cs ^ (d & 7);                // global chunk (0..7)
      gV[j] = Vg + baseV + (size_t)d * S + c * 8;    // + k0 per tile
      lV[j] = t * 8;
    }
  }

  const f32x4 fz = {0.f, 0.f, 0.f, 0.f};

  for (int pass = 0; pass < 2; ++pass) {
    const int qtile = pass ? px : 15 - px;     // heavy first
    const int q0 = qtile * 128 + hl * 64;
    const int ktmax = 2 * qtile + hl;

    __syncthreads();

    bf16x8 qf[4];
#pragma unroll
    for (int kb = 0; kb < 4; ++kb)
      qf[kb] = *(const bf16x8*)&Q[baseQK +
          (size_t)(q0 + wave * 16 + m16) * D + kb * 32 + quad * 8];

    float li[4] = {0.f, 0.f, 0.f, 0.f};
    f32x4 oacc[8];
#pragma unroll
    for (int dt = 0; dt < 8; ++dt) oacc[dt] = fz;

#pragma unroll
    for (int j = 0; j < 4; ++j) GLOAD_LDS16(gK[j], &Kt[0][lK[j]]);

    for (int kt = 0; kt <= ktmax; ++kt) {
      const int k0 = kt * 64;
      const int cb = kt & 1;
      DRAIN_VMEM();
      __syncthreads();   // K(kt) resident; all waves done with Vt(kt-1), Kt[cb^1]

#pragma unroll
      for (int j = 0; j < 4; ++j) GLOAD_LDS16(gV[j] + k0, &Vt[lV[j]]);
      float madd[4];
#pragma unroll
      for (int nt = 0; nt < 4; ++nt)
        madd[nt] = mexp_g[b * S + k0 + nt * 16 + m16];
      if (kt < ktmax) {
#pragma unroll
        for (int j = 0; j < 4; ++j)
          GLOAD_LDS16(gK[j] + (size_t)(k0 + 64) * D, &Kt[cb ^ 1][lK[j]]);
      }

      f32x4 sacc[4];
#pragma unroll
      for (int nt = 0; nt < 4; ++nt) sacc[nt] = fz;
#pragma unroll
      for (int nt = 0; nt < 4; ++nt)
#pragma unroll
        for (int kb = 0; kb < 4; ++kb) {
          const int c = kb * 4 + quad;
          const int cs = (c & 8) | ((c ^ m16) & 7);
          bf16x8 kf = *(const bf16x8*)&Kt[cb][(nt * 16 + m16) * 128 + cs * 8];
          sacc[nt] = MFMA(qf[kb], kf, sacc[nt]);
        }

      if (kt < ktmax) { asm volatile("s_waitcnt vmcnt(4)" ::: "memory"); }
      else           { asm volatile("s_waitcnt vmcnt(0)" ::: "memory"); }
      __builtin_amdgcn_sched_barrier(0);

      const int R0   = q0 + wave * 16;
      const int prow = wave * 16 + quad * 4;
      if (k0 + 63 > R0) {
#pragma unroll
        for (int rg = 0; rg < 4; ++rg) {
          const int row = R0 + quad * 4 + rg;
          const int pr  = prow + rg;
          float ps = 0.f;
#pragma unroll
          for (int nt = 0; nt < 4; ++nt) {
            const int col = k0 + nt * 16 + m16;
            const float p = (col > row) ? 0.f : __expf(sacc[nt][rg] + madd[nt]);
            ps += p;
            const int c = nt * 2 + (m16 >> 3);
            Pt[pr * 64 + ((c ^ pr) & 7) * 8 + (m16 & 7)] = f2bf(p);
          }
          li[rg] += ps;
        }
      } else {
#pragma unroll
        for (int rg = 0; rg < 4; ++rg) {
          const int pr = prow + rg;
          float ps = 0.f;
#pragma unroll
          for (int nt = 0; nt < 4; ++nt) {
            const float p = __expf(sacc[nt][rg] + madd[nt]);
            ps += p;
            const int c = nt * 2 + (m16 >> 3);
            Pt[pr * 64 + ((c ^ pr) & 7) * 8 + (m16 & 7)] = f2bf(p);
          }
          li[rg] += ps;
        }
      }
      FENCE_LDS();

#pragma unroll
      for (int kb = 0; kb < 2; ++kb) {
        const int c = kb * 4 + quad;
        const int cs = (c ^ m16) & 7;
        bf16x8 pf = *(const bf16x8*)&Pt[(wave * 16 + m16) * 64 + cs * 8];
#pragma unroll
        for (int dt = 0; dt < 8; ++dt) {
          bf16x8 vf = *(const bf16x8*)&Vt[(dt * 16 + m16) * 64 + cs * 8];
          oacc[dt] = MFMA(pf, vf, oacc[dt]);
        }
      }
    }

#pragma unroll
    for (int rg = 0; rg < 4; ++rg) {
      float ls = li[rg];
#pragma unroll
      for (int mk = 1; mk < 16; mk <<= 1) ls += __shfl_xor(ls, mk, 64);
      const float inv = 1.0f / ls;
      const int srow = q0 + wave * 16 + quad * 4 + rg;
#pragma unroll
      for (int dt = 0; dt < 8; ++dt) {
        const int e = h * 128 + dt * 16 + m16;
        ctx[((size_t)b * S + srow) * 2048 + e] = f2bf(oacc[dt][rg] * inv);
      }
    }
  }
}

// ---------------------------------------------------------------------------
extern "C" void kernel_launch(void* const* d_in, const int* in_sizes, int n_in,
                              void* d_out, int out_size, void* d_ws, size_t ws_size,
                              hipStream_t stream) {
  (void)in_sizes; (void)n_in; (void)out_size; (void)ws_size;
  const int Bz = 2, S = 2048, E = 2048, H = 16;
  const size_t NX = (size_t)Bz * S * E;   // 8388608
  const size_t NW = (size_t)E * E;        // 4194304

  // ws layout (~117.5 MB)
  char* ws = (char*)d_ws;
  int*   flags = (int*)ws;                 // 6 ints
  float* mexp  = (float*)(ws + 256);       // 16 KB
  u16* xc  = (u16*)(ws + 256 + 16384);
  u16* Wqc = xc + NX;                      // Wq,Wk,Wv contiguous = fused B
  u16* Qr  = Wqc + 4 * NW;                 // [B,H,S,D]; Qr,Kr,Vt contiguous
  u16* Kr  = Qr + NX;                      // [B,H,S,D]
  u16* Vt  = Kr + NX;                      // [B,H,D,S]
  u16* ctx = Vt + NX;                      // [B,S,E]
  u16* Woc = Wqc + 3 * NW;

  probe_all<<<6, 256, 0, stream>>>((const u16*)d_in[0], (const u16*)d_in[1],
                                   (const u16*)d_in[2], (const u16*)d_in[3],
                                   (const u16*)d_in[4], (const u16*)d_in[5], flags);

  prep_all<<<12304, 256, 0, stream>>>(d_in[0], d_in[2], d_in[3], d_in[4],
                                      d_in[5], d_in[1], xc, mexp, flags);

  // fused QKV projection: C[4096, 6144] = xc @ [Wq;Wk;Wv]^T
  gemm_bt<<<dim3(48, 32), 256, 0, stream>>>(xc, Wqc, Qr, E, 3);
  rope_kernel<<<(Bz * H * S * 64) / 256, 256, 0, stream>>>(Qr, Kr);
  flash_attn<<<dim3(16, Bz * H), 256, 0, stream>>>(Qr, Kr, Vt, mexp, ctx);
  gemm_bt<<<dim3(16, 32), 256, 0, stream>>>(ctx, Woc, d_out, E, 2);
}